// Round 6
// baseline (287.669 us; speedup 1.0000x reference)
//
#include <hip/hip_runtime.h>
#include <hip/hip_fp16.h>
#include <cstdint>
#include <cstddef>

#define NEG_SLOPE 0.2f
#define LN_EPS 1e-5f

constexpr int BS = 256;

typedef _Float16 f16x8 __attribute__((ext_vector_type(8)));
typedef float f32x4 __attribute__((ext_vector_type(4)));

// ============================ CSR build ============================

// deg must be zeroed (memsetAsync). Counts edges + self loops in one pass.
__global__ void k_hist(const int* __restrict__ dst, int* __restrict__ deg,
                       int e, int etot) {
    int i = blockIdx.x * BS + threadIdx.x;
    if (i < e)         atomicAdd(&deg[dst[i]], 1);
    else if (i < etot) atomicAdd(&deg[i - e], 1);   // self loop
}

__global__ void k_scanA(const int* __restrict__ deg, int* __restrict__ offs,
                        int* __restrict__ bsums, int n) {
    __shared__ int sm[BS];
    int i = blockIdx.x * BS + threadIdx.x;
    int v = (i < n) ? deg[i] : 0;
    sm[threadIdx.x] = v;
    __syncthreads();
    for (int o = 1; o < BS; o <<= 1) {
        int t = (threadIdx.x >= o) ? sm[threadIdx.x - o] : 0;
        __syncthreads();
        sm[threadIdx.x] += t;
        __syncthreads();
    }
    if (i < n) offs[i] = sm[threadIdx.x] - v;  // exclusive
    if (threadIdx.x == BS - 1) bsums[blockIdx.x] = sm[BS - 1];
}

__global__ void k_scanB(int* __restrict__ bsums, int nb) {
    __shared__ int sm[BS];
    int v = (threadIdx.x < nb) ? bsums[threadIdx.x] : 0;
    sm[threadIdx.x] = v;
    __syncthreads();
    for (int o = 1; o < BS; o <<= 1) {
        int t = (threadIdx.x >= o) ? sm[threadIdx.x - o] : 0;
        __syncthreads();
        sm[threadIdx.x] += t;
        __syncthreads();
    }
    bsums[threadIdx.x] = sm[threadIdx.x] - v;  // exclusive
}

// final offsets + cursor init + segmented nid fill (deg still valid here)
__global__ void k_scanC(int* __restrict__ offs, const int* __restrict__ bsums,
                        const int* __restrict__ deg, int* __restrict__ cursor,
                        int* __restrict__ nid, int n, int total) {
    int i = blockIdx.x * BS + threadIdx.x;
    if (i < n) {
        int v = offs[i] + bsums[blockIdx.x];
        offs[i] = v;
        cursor[i] = v;
        int d = deg[i];
        for (int j = v; j < v + d; ++j) nid[j] = i;
    }
    if (i == 0) offs[n] = total;
}

// 4 independent atomic+scatter chains per thread (latency-bound kernel: MLP)
__global__ void k_fill(const int* __restrict__ src, const int* __restrict__ dst,
                       int* __restrict__ cursor, int* __restrict__ csr, int e, int n) {
    int i0 = blockIdx.x * (BS * 4) + threadIdx.x;
    #pragma unroll
    for (int u = 0; u < 4; ++u) {
        int i = i0 + u * BS;
        if (i < e) {
            int pos = atomicAdd(&cursor[dst[i]], 1);
            csr[pos] = src[i];
        } else if (i < e + n) {
            int nn = i - e;
            int pos = atomicAdd(&cursor[nn], 1);
            csr[pos] = nn;  // self loop
        }
    }
}

// per-slot (src byte-offset, weight); tail [etot, etot+16) zero-padded so the
// agg loop can read past segment ends with w forced 0 and no index clamping.
__global__ void k_edgew(const int* __restrict__ csr, const int* __restrict__ nid,
                        const float* __restrict__ as_, const float* __restrict__ ad_,
                        int2* __restrict__ sw, int etot) {
    int j = blockIdx.x * BS + threadIdx.x;
    if (j < etot) {
        int s = csr[j];
        float t = as_[s] + ad_[nid[j]];
        t = t > 0.f ? t : NEG_SLOPE * t;
        float w = __expf(fminf(t, 70.f));
        sw[j] = make_int2(s << 8, __float_as_int(w));   // s*256 = fp16 row byte off
    } else if (j < etot + 16) {
        sw[j] = make_int2(0, 0);
    }
}

// ============================ fp16 conversions ============================

__global__ void k_cvt_x(const float* __restrict__ x, const int* __restrict__ cid,
                        const float* __restrict__ emb, _Float16* __restrict__ xb,
                        int n, int npad) {
    int r = blockIdx.x * 8 + (threadIdx.x >> 5);
    int c = threadIdx.x & 31;
    if (r >= npad) return;
    _Float16* row = xb + (size_t)r * 160;
    if (r < n) {
        const float* xr = x + (size_t)r * 128;
        #pragma unroll
        for (int k = 0; k < 4; ++k) row[c + 32 * k] = (_Float16)xr[c + 32 * k];
        float v = (c < 8) ? emb[cid[r] * 8 + c] : 0.f;
        row[128 + c] = (_Float16)v;
    } else {
        #pragma unroll
        for (int k = 0; k < 5; ++k) row[c + 32 * k] = (_Float16)0.f;
    }
}

// both weight transposes in one launch: [0,20480)->Wt1 (K=136,KP=160),
// [20480,36864)->Wt2 (K=KP=128)
__global__ void k_cvt_w12(const float* __restrict__ W1, const float* __restrict__ W2,
                          _Float16* __restrict__ Wt1, _Float16* __restrict__ Wt2) {
    int idx = blockIdx.x * BS + threadIdx.x;
    if (idx < 128 * 160) {
        int nn = idx / 160, k = idx - nn * 160;
        Wt1[idx] = (_Float16)((k < 136) ? W1[(size_t)k * 128 + nn] : 0.f);
    } else if (idx < 128 * 160 + 128 * 128) {
        int j = idx - 128 * 160;
        int nn = j >> 7, k = j & 127;
        Wt2[j] = (_Float16)W2[(size_t)k * 128 + nn];
    }
}

// ============================ MFMA GEMM ============================
// One wave per 32 rows x 128 cols (1563 waves -> >1/SIMD). Operand roles
// swapped so D holds h^T fragments (lane owns 4 consecutive cols of one row).
template<int KP>
__global__ __launch_bounds__(64) void k_gemm_mfma(
    const _Float16* __restrict__ A, const _Float16* __restrict__ Bt,
    const float* __restrict__ a_src, const float* __restrict__ a_dst,
    _Float16* __restrict__ hb, float* __restrict__ as_,
    float* __restrict__ ad_, int n)
{
    int lane = threadIdx.x;
    int r15 = lane & 15, q = lane >> 4;
    int rowBase = blockIdx.x * 32;

    f32x4 acc[8][2] = {};   // [s: col tile][t: row tile]

    const _Float16* Wp[8];
    #pragma unroll
    for (int s = 0; s < 8; ++s)
        Wp[s] = Bt + (size_t)(s * 16 + r15) * KP + q * 8;
    const _Float16* Xp[2];
    #pragma unroll
    for (int t = 0; t < 2; ++t)
        Xp[t] = A + (size_t)(rowBase + t * 16 + r15) * KP + q * 8;

    #pragma unroll
    for (int k0 = 0; k0 < KP; k0 += 32) {
        f16x8 wv[8], xv[2];
        #pragma unroll
        for (int s = 0; s < 8; ++s) wv[s] = *(const f16x8*)(Wp[s] + k0);
        #pragma unroll
        for (int t = 0; t < 2; ++t) xv[t] = *(const f16x8*)(Xp[t] + k0);
        #pragma unroll
        for (int s = 0; s < 8; ++s)
            #pragma unroll
            for (int t = 0; t < 2; ++t)
                acc[s][t] = __builtin_amdgcn_mfma_f32_16x16x32_f16(wv[s], xv[t], acc[s][t], 0, 0, 0);
    }

    float4 asv[8], adv[8];
    #pragma unroll
    for (int s = 0; s < 8; ++s) {
        asv[s] = *(const float4*)&a_src[s * 16 + q * 4];
        adv[s] = *(const float4*)&a_dst[s * 16 + q * 4];
    }

    #pragma unroll
    for (int t = 0; t < 2; ++t) {
        int row = rowBase + t * 16 + r15;
        bool ok = row < n;
        float vs = 0.f, vd = 0.f;
        #pragma unroll
        for (int s = 0; s < 8; ++s) {
            f32x4 d = acc[s][t];
            vs += d[0]*asv[s].x + d[1]*asv[s].y + d[2]*asv[s].z + d[3]*asv[s].w;
            vd += d[0]*adv[s].x + d[1]*adv[s].y + d[2]*adv[s].z + d[3]*adv[s].w;
            if (ok) {
                ushort4 u;
                u.x = __half_as_ushort(__float2half_rn(d[0]));
                u.y = __half_as_ushort(__float2half_rn(d[1]));
                u.z = __half_as_ushort(__float2half_rn(d[2]));
                u.w = __half_as_ushort(__float2half_rn(d[3]));
                *(ushort4*)&hb[(size_t)row * 128 + s * 16 + q * 4] = u;
            }
        }
        vs += __shfl_xor(vs, 16); vs += __shfl_xor(vs, 32);
        vd += __shfl_xor(vd, 16); vd += __shfl_xor(vd, 32);
        if (ok && q == 0) { as_[row] = vs; ad_[row] = vd; }
    }
}

// ============================ aggregation ============================
// one wave per dst node. Lanes 0-15 vector-load 16 (row_off, w) pairs; each
// edge's offset/weight is readlane'd into SGPRs, so the row gather is
// global_load_dword v,(lane*4),s[row] — zero per-edge vector address math —
// and the fma takes w as an SGPR operand. OOB slots (scalar cselect) get w=0
// and harmlessly gather the next segment's rows (sw end-padded by 16 zeros).
template<bool LN_ELU, bool OUT_HALF>
__global__ __launch_bounds__(256) void k_agg(
    const _Float16* __restrict__ hb, const int2* __restrict__ sw,
    const int* __restrict__ offs, const float* __restrict__ bias,
    const float* __restrict__ ln_g, const float* __restrict__ ln_b,
    void* __restrict__ outv, int n_nodes)
{
    int wave = threadIdx.x >> 6, lane = threadIdx.x & 63;
    int n = blockIdx.x * 4 + wave;
    if (n >= n_nodes) return;
    int start = __builtin_amdgcn_readfirstlane(offs[n]);
    int end   = __builtin_amdgcn_readfirstlane(offs[n + 1]);

    float acc0 = 0.f, acc1 = 0.f, dsum = 0.f;
    for (int j = start; j < end; j += 16) {
        int rem = end - j;                         // uniform (SGPR)
        int2 p = sw[j + (lane & 15)];
        #pragma unroll
        for (int u = 0; u < 16; ++u) {
            int offB = __builtin_amdgcn_readlane(p.x, u);   // SGPR
            int wb   = __builtin_amdgcn_readlane(p.y, u);   // SGPR
            float w  = (u < rem) ? __int_as_float(wb) : 0.f; // scalar cselect
            const __half2* rowp = (const __half2*)((const char*)hb + offB);
            float2 f = __half22float2(rowp[lane]);
            acc0 = fmaf(w, f.x, acc0);
            acc1 = fmaf(w, f.y, acc1);
            dsum += w;
        }
    }

    float inv = 1.f / dsum;
    float2 bv = ((const float2*)bias)[lane];
    float v0 = acc0 * inv + bv.x;
    float v1 = acc1 * inv + bv.y;

    if (LN_ELU) {
        float s1 = v0 + v1, s2 = v0 * v0 + v1 * v1;
        #pragma unroll
        for (int o = 32; o; o >>= 1) { s1 += __shfl_xor(s1, o); s2 += __shfl_xor(s2, o); }
        float mean = s1 * (1.f / 128.f);
        float var  = s2 * (1.f / 128.f) - mean * mean;
        float r = rsqrtf(var + LN_EPS);
        float2 gv  = ((const float2*)ln_g)[lane];
        float2 lbv = ((const float2*)ln_b)[lane];
        v0 = (v0 - mean) * r * gv.x + lbv.x;
        v1 = (v1 - mean) * r * gv.y + lbv.y;
        v0 = v0 > 0.f ? v0 : __expf(v0) - 1.f;
        v1 = v1 > 0.f ? v1 : __expf(v1) - 1.f;
    }

    if (OUT_HALF) {
        _Float16* out = (_Float16*)outv;
        ((__half2*)(out + (size_t)n * 128))[lane] = __floats2half2_rn(v0, v1);
    } else {
        float* out = (float*)outv;
        ((float2*)(out + (size_t)n * 128))[lane] = make_float2(v0, v1);
    }
}

// ============================ launch ============================

extern "C" void kernel_launch(void* const* d_in, const int* in_sizes, int n_in,
                              void* d_out, int out_size, void* d_ws, size_t ws_size,
                              hipStream_t stream) {
    const float* x_base   = (const float*)d_in[0];
    const int*   cell_ids = (const int*)d_in[1];
    const int*   eidx     = (const int*)d_in[2];
    const float* cell_emb = (const float*)d_in[3];
    const float* W1     = (const float*)d_in[4];
    const float* a_src1 = (const float*)d_in[5];
    const float* a_dst1 = (const float*)d_in[6];
    const float* b1     = (const float*)d_in[7];
    const float* ln_g   = (const float*)d_in[8];
    const float* ln_b   = (const float*)d_in[9];
    const float* W2     = (const float*)d_in[10];
    const float* a_src2 = (const float*)d_in[11];
    const float* a_dst2 = (const float*)d_in[12];
    const float* b2     = (const float*)d_in[13];

    const int N = in_sizes[0] / 128;
    const int E = in_sizes[2] / 2;
    const int ETOT = E + N;
    const int gridG = (N + 31) / 32;
    const int Npad  = gridG * 32;

    const int* esrc = eidx;
    const int* edst = eidx + E;

    auto align = [](size_t v) { return (v + 255) & ~(size_t)255; };
    char* p = (char*)d_ws;
    int*   deg    = (int*)p;   p += align((size_t)N * 4);
    int*   offs   = (int*)p;   p += align((size_t)(N + 1) * 4);
    int*   cursor = (int*)p;   p += align((size_t)N * 4);
    int*   bsums  = (int*)p;   p += align(1024);
    int*   csr    = (int*)p;   p += align((size_t)ETOT * 4);
    int*   nid    = (int*)p;   p += align((size_t)ETOT * 4);
    int2*  sw     = (int2*)p;  p += align((size_t)(ETOT + 16) * 8);
    _Float16* xb  = (_Float16*)p; p += align((size_t)Npad * 160 * 2);
    _Float16* yb  = (_Float16*)p; p += align((size_t)Npad * 128 * 2);
    _Float16* hb  = (_Float16*)p; p += align((size_t)N * 128 * 2);
    _Float16* Wt1 = (_Float16*)p; p += align((size_t)128 * 160 * 2);
    _Float16* Wt2 = (_Float16*)p; p += align((size_t)128 * 128 * 2);
    float* as_    = (float*)p; p += align((size_t)N * 4);
    float* ad_    = (float*)p; p += align((size_t)N * 4);
    (void)ws_size; (void)n_in; (void)out_size;

    const int nbN = (N + BS - 1) / BS;   // 196 (<=256 required by k_scanB)
    const int nbE = (ETOT + BS - 1) / BS;

    hipMemsetAsync(deg, 0, (size_t)N * 4, stream);
    k_hist<<<nbE, BS, 0, stream>>>(edst, deg, E, ETOT);
    k_scanA<<<nbN, BS, 0, stream>>>(deg, offs, bsums, N);
    k_scanB<<<1, BS, 0, stream>>>(bsums, nbN);
    k_scanC<<<nbN, BS, 0, stream>>>(offs, bsums, deg, cursor, nid, N, ETOT);
    k_fill<<<(ETOT + BS * 4 - 1) / (BS * 4), BS, 0, stream>>>(esrc, edst, cursor, csr, E, N);

    k_cvt_x<<<(Npad + 7) / 8, BS, 0, stream>>>(x_base, cell_ids, cell_emb, xb, N, Npad);
    k_cvt_w12<<<(128 * 160 + 128 * 128 + BS - 1) / BS, BS, 0, stream>>>(W1, W2, Wt1, Wt2);

    // ---- layer 1
    k_gemm_mfma<160><<<gridG, 64, 0, stream>>>(xb, Wt1, a_src1, a_dst1, hb, as_, ad_, N);
    k_edgew<<<(ETOT + 16 + BS - 1) / BS, BS, 0, stream>>>(csr, nid, as_, ad_, sw, ETOT);
    k_agg<true, true><<<(N + 3) / 4, 256, 0, stream>>>(
        hb, sw, offs, b1, ln_g, ln_b, (void*)yb, N);

    // ---- layer 2
    k_gemm_mfma<128><<<gridG, 64, 0, stream>>>(yb, Wt2, a_src2, a_dst2, hb, as_, ad_, N);
    k_edgew<<<(ETOT + 16 + BS - 1) / BS, BS, 0, stream>>>(csr, nid, as_, ad_, sw, ETOT);
    k_agg<false, false><<<(N + 3) / 4, 256, 0, stream>>>(
        hb, sw, offs, b2, ln_g, ln_b, d_out, N);
}

// Round 7
// 272.342 us; speedup vs baseline: 1.0563x; 1.0563x over previous
//
#include <hip/hip_runtime.h>
#include <hip/hip_fp16.h>
#include <cstdint>
#include <cstddef>

#define NEG_SLOPE 0.2f
#define LN_EPS 1e-5f

constexpr int BS = 256;

typedef _Float16 f16x8 __attribute__((ext_vector_type(8)));
typedef float f32x4 __attribute__((ext_vector_type(4)));

// ============================ linked-list CSR ============================
// head[] must be initialized to -1 (memsetAsync 0xFF). One coalesced int2
// write per edge; the only random op is the L2-resident 4B atomicExch.
__global__ void k_link(const int* __restrict__ esrc, const int* __restrict__ edst,
                       int* __restrict__ head, int2* __restrict__ nxt2,
                       int e, int etot) {
    int i = blockIdx.x * BS + threadIdx.x;
    if (i >= etot) return;
    int s, d;
    if (i < e) { s = esrc[i]; d = edst[i]; }
    else       { s = d = i - e; }          // self loop
    int old = atomicExch(&head[d], i);
    nxt2[i] = make_int2(old, s);           // {next ptr, src node}
}

// walk chain to count degree + block exclusive scan (Hillis-Steele)
__global__ void k_countscan(const int* __restrict__ head, const int2* __restrict__ nxt2,
                            int* __restrict__ offs, int* __restrict__ bsums, int n) {
    __shared__ int sm[BS];
    int i = blockIdx.x * BS + threadIdx.x;
    int len = 0;
    if (i < n) {
        int j = head[i];
        while (j >= 0) { ++len; j = nxt2[j].x; }
    }
    sm[threadIdx.x] = len;
    __syncthreads();
    for (int o = 1; o < BS; o <<= 1) {
        int t = (threadIdx.x >= o) ? sm[threadIdx.x - o] : 0;
        __syncthreads();
        sm[threadIdx.x] += t;
        __syncthreads();
    }
    if (i < n) offs[i] = sm[threadIdx.x] - len;   // exclusive (block-local)
    if (threadIdx.x == BS - 1) bsums[blockIdx.x] = sm[BS - 1];
}

// single-block scan of block sums (nb <= 256; N=50000 -> nb=196)
__global__ void k_scanB(int* __restrict__ bsums, int nb) {
    __shared__ int sm[BS];
    int v = (threadIdx.x < nb) ? bsums[threadIdx.x] : 0;
    sm[threadIdx.x] = v;
    __syncthreads();
    for (int o = 1; o < BS; o <<= 1) {
        int t = (threadIdx.x >= o) ? sm[threadIdx.x - o] : 0;
        __syncthreads();
        sm[threadIdx.x] += t;
        __syncthreads();
    }
    bsums[threadIdx.x] = sm[threadIdx.x] - v;  // exclusive
}

__global__ void k_scanC(int* __restrict__ offs, const int* __restrict__ bsums,
                        int n, int total) {
    int i = blockIdx.x * BS + threadIdx.x;
    if (i < n) offs[i] += bsums[blockIdx.x];
    if (i == 0) offs[n] = total;
}

// per-layer: walk chain, compute w = exp(leaky(as[src]+ad[n])), write the
// node's sw segment sequentially (adjacent threads own adjacent segments ->
// L2 write-combining, no random scatter).
__global__ void k_edgeww(const int* __restrict__ head, const int2* __restrict__ nxt2,
                         const int* __restrict__ offs, const float* __restrict__ as_,
                         const float* __restrict__ ad_, int2* __restrict__ sw, int n) {
    int i = blockIdx.x * BS + threadIdx.x;
    if (i >= n) return;
    float adv = ad_[i];
    int pos = offs[i];
    int j = head[i];
    while (j >= 0) {
        int2 p = nxt2[j];
        float t = as_[p.y] + adv;
        t = t > 0.f ? t : NEG_SLOPE * t;
        float w = __expf(fminf(t, 70.f));
        sw[pos++] = make_int2(p.y, __float_as_int(w));
        j = p.x;
    }
}

// ============================ fp16 conversions ============================

__global__ void k_cvt_x(const float* __restrict__ x, const int* __restrict__ cid,
                        const float* __restrict__ emb, _Float16* __restrict__ xb,
                        int n, int npad) {
    int r = blockIdx.x * 8 + (threadIdx.x >> 5);
    int c = threadIdx.x & 31;
    if (r >= npad) return;
    _Float16* row = xb + (size_t)r * 160;
    if (r < n) {
        const float* xr = x + (size_t)r * 128;
        #pragma unroll
        for (int k = 0; k < 4; ++k) row[c + 32 * k] = (_Float16)xr[c + 32 * k];
        float v = (c < 8) ? emb[cid[r] * 8 + c] : 0.f;
        row[128 + c] = (_Float16)v;
    } else {
        #pragma unroll
        for (int k = 0; k < 5; ++k) row[c + 32 * k] = (_Float16)0.f;
    }
}

// both weight transposes in one launch
__global__ void k_cvt_w12(const float* __restrict__ W1, const float* __restrict__ W2,
                          _Float16* __restrict__ Wt1, _Float16* __restrict__ Wt2) {
    int idx = blockIdx.x * BS + threadIdx.x;
    if (idx < 128 * 160) {
        int nn = idx / 160, k = idx - nn * 160;
        Wt1[idx] = (_Float16)((k < 136) ? W1[(size_t)k * 128 + nn] : 0.f);
    } else if (idx < 128 * 160 + 128 * 128) {
        int j = idx - 128 * 160;
        int nn = j >> 7, k = j & 127;
        Wt2[j] = (_Float16)W2[(size_t)k * 128 + nn];
    }
}

// ============================ MFMA GEMM ============================
// One wave per 64 rows x 128 cols; operand roles swapped so D holds h^T
// fragments (lane owns 4 consecutive cols of one row per (s,t) tile).
template<int KP>
__global__ __launch_bounds__(64) void k_gemm_mfma(
    const _Float16* __restrict__ A, const _Float16* __restrict__ Bt,
    const float* __restrict__ a_src, const float* __restrict__ a_dst,
    _Float16* __restrict__ hb, float* __restrict__ as_,
    float* __restrict__ ad_, int n)
{
    int lane = threadIdx.x;
    int r15 = lane & 15, q = lane >> 4;
    int rowBase = blockIdx.x * 64;

    f32x4 acc[8][4] = {};   // [s: col tile][t: row tile]

    const _Float16* Wp[8];
    #pragma unroll
    for (int s = 0; s < 8; ++s)
        Wp[s] = Bt + (size_t)(s * 16 + r15) * KP + q * 8;
    const _Float16* Xp[4];
    #pragma unroll
    for (int t = 0; t < 4; ++t)
        Xp[t] = A + (size_t)(rowBase + t * 16 + r15) * KP + q * 8;

    #pragma unroll
    for (int k0 = 0; k0 < KP; k0 += 32) {
        f16x8 wv[8], xv[4];
        #pragma unroll
        for (int s = 0; s < 8; ++s) wv[s] = *(const f16x8*)(Wp[s] + k0);
        #pragma unroll
        for (int t = 0; t < 4; ++t) xv[t] = *(const f16x8*)(Xp[t] + k0);
        #pragma unroll
        for (int s = 0; s < 8; ++s)
            #pragma unroll
            for (int t = 0; t < 4; ++t)
                acc[s][t] = __builtin_amdgcn_mfma_f32_16x16x32_f16(wv[s], xv[t], acc[s][t], 0, 0, 0);
    }

    float4 asv[8], adv[8];
    #pragma unroll
    for (int s = 0; s < 8; ++s) {
        asv[s] = *(const float4*)&a_src[s * 16 + q * 4];
        adv[s] = *(const float4*)&a_dst[s * 16 + q * 4];
    }

    #pragma unroll
    for (int t = 0; t < 4; ++t) {
        int row = rowBase + t * 16 + r15;
        bool ok = row < n;
        float vs = 0.f, vd = 0.f;
        #pragma unroll
        for (int s = 0; s < 8; ++s) {
            f32x4 d = acc[s][t];
            vs += d[0]*asv[s].x + d[1]*asv[s].y + d[2]*asv[s].z + d[3]*asv[s].w;
            vd += d[0]*adv[s].x + d[1]*adv[s].y + d[2]*adv[s].z + d[3]*adv[s].w;
            if (ok) {
                ushort4 u;
                u.x = __half_as_ushort(__float2half_rn(d[0]));
                u.y = __half_as_ushort(__float2half_rn(d[1]));
                u.z = __half_as_ushort(__float2half_rn(d[2]));
                u.w = __half_as_ushort(__float2half_rn(d[3]));
                *(ushort4*)&hb[(size_t)row * 128 + s * 16 + q * 4] = u;
            }
        }
        vs += __shfl_xor(vs, 16); vs += __shfl_xor(vs, 32);
        vd += __shfl_xor(vd, 16); vd += __shfl_xor(vd, 32);
        if (ok && q == 0) { as_[row] = vs; ad_[row] = vd; }
    }
}

// ============================ aggregation ============================
// one wave per dst node; (src,w) precomputed in sw[]; 16 row-gathers in
// flight; dsum wave-uniform (no reduction).
template<bool LN_ELU, bool OUT_HALF>
__global__ __launch_bounds__(256) void k_agg(
    const _Float16* __restrict__ hb, const int2* __restrict__ sw,
    const int* __restrict__ offs, const float* __restrict__ bias,
    const float* __restrict__ ln_g, const float* __restrict__ ln_b,
    void* __restrict__ outv, int n_nodes)
{
    int wave = threadIdx.x >> 6, lane = threadIdx.x & 63;
    int n = blockIdx.x * 4 + wave;
    if (n >= n_nodes) return;
    int start = __builtin_amdgcn_readfirstlane(offs[n]);
    int end   = __builtin_amdgcn_readfirstlane(offs[n + 1]);

    float acc0 = 0.f, acc1 = 0.f, dsum = 0.f;
    for (int j = start; j < end; j += 16) {
        int rem = end - j;   // uniform
        int sj[16]; float wj[16];
        #pragma unroll
        for (int u = 0; u < 16; ++u) {
            int idx = (u < rem) ? (j + u) : j;   // OOB slots alias edge j (w=0)
            int2 p = sw[idx];
            sj[u] = p.x;
            wj[u] = (u < rem) ? __int_as_float(p.y) : 0.f;
        }
        __half2 hv[16];
        #pragma unroll
        for (int u = 0; u < 16; ++u)
            hv[u] = ((const __half2*)(hb + (size_t)sj[u] * 128))[lane];
        #pragma unroll
        for (int u = 0; u < 16; ++u) {
            float2 f = __half22float2(hv[u]);
            acc0 = fmaf(wj[u], f.x, acc0);
            acc1 = fmaf(wj[u], f.y, acc1);
            dsum += wj[u];
        }
    }

    float inv = 1.f / dsum;
    float2 bv = ((const float2*)bias)[lane];
    float v0 = acc0 * inv + bv.x;
    float v1 = acc1 * inv + bv.y;

    if (LN_ELU) {
        float s1 = v0 + v1, s2 = v0 * v0 + v1 * v1;
        #pragma unroll
        for (int o = 32; o; o >>= 1) { s1 += __shfl_xor(s1, o); s2 += __shfl_xor(s2, o); }
        float mean = s1 * (1.f / 128.f);
        float var  = s2 * (1.f / 128.f) - mean * mean;
        float r = rsqrtf(var + LN_EPS);
        float2 gv  = ((const float2*)ln_g)[lane];
        float2 lbv = ((const float2*)ln_b)[lane];
        v0 = (v0 - mean) * r * gv.x + lbv.x;
        v1 = (v1 - mean) * r * gv.y + lbv.y;
        v0 = v0 > 0.f ? v0 : __expf(v0) - 1.f;
        v1 = v1 > 0.f ? v1 : __expf(v1) - 1.f;
    }

    if (OUT_HALF) {
        _Float16* out = (_Float16*)outv;
        ((__half2*)(out + (size_t)n * 128))[lane] = __floats2half2_rn(v0, v1);
    } else {
        float* out = (float*)outv;
        ((float2*)(out + (size_t)n * 128))[lane] = make_float2(v0, v1);
    }
}

// ============================ launch ============================

extern "C" void kernel_launch(void* const* d_in, const int* in_sizes, int n_in,
                              void* d_out, int out_size, void* d_ws, size_t ws_size,
                              hipStream_t stream) {
    const float* x_base   = (const float*)d_in[0];
    const int*   cell_ids = (const int*)d_in[1];
    const int*   eidx     = (const int*)d_in[2];
    const float* cell_emb = (const float*)d_in[3];
    const float* W1     = (const float*)d_in[4];
    const float* a_src1 = (const float*)d_in[5];
    const float* a_dst1 = (const float*)d_in[6];
    const float* b1     = (const float*)d_in[7];
    const float* ln_g   = (const float*)d_in[8];
    const float* ln_b   = (const float*)d_in[9];
    const float* W2     = (const float*)d_in[10];
    const float* a_src2 = (const float*)d_in[11];
    const float* a_dst2 = (const float*)d_in[12];
    const float* b2     = (const float*)d_in[13];

    const int N = in_sizes[0] / 128;
    const int E = in_sizes[2] / 2;
    const int ETOT = E + N;
    const int gridG = (N + 63) / 64;
    const int Npad  = gridG * 64;

    const int* esrc = eidx;
    const int* edst = eidx + E;

    auto align = [](size_t v) { return (v + 255) & ~(size_t)255; };
    char* p = (char*)d_ws;
    int*   head   = (int*)p;   p += align((size_t)N * 4);
    int*   offs   = (int*)p;   p += align((size_t)(N + 1) * 4);
    int*   bsums  = (int*)p;   p += align(1024);
    int2*  nxt2   = (int2*)p;  p += align((size_t)ETOT * 8);
    int2*  sw     = (int2*)p;  p += align((size_t)ETOT * 8);
    _Float16* xb  = (_Float16*)p; p += align((size_t)Npad * 160 * 2);
    _Float16* yb  = (_Float16*)p; p += align((size_t)Npad * 128 * 2);
    _Float16* hb  = (_Float16*)p; p += align((size_t)N * 128 * 2);
    _Float16* Wt1 = (_Float16*)p; p += align((size_t)128 * 160 * 2);
    _Float16* Wt2 = (_Float16*)p; p += align((size_t)128 * 128 * 2);
    float* as_    = (float*)p; p += align((size_t)N * 4);
    float* ad_    = (float*)p; p += align((size_t)N * 4);
    (void)ws_size; (void)n_in; (void)out_size;

    const int nbN = (N + BS - 1) / BS;   // 196 (<=256 required by k_scanB)
    const int nbE = (ETOT + BS - 1) / BS;

    hipMemsetAsync(head, 0xFF, (size_t)N * 4, stream);   // head = -1
    k_link<<<nbE, BS, 0, stream>>>(esrc, edst, head, nxt2, E, ETOT);
    k_countscan<<<nbN, BS, 0, stream>>>(head, nxt2, offs, bsums, N);
    k_scanB<<<1, BS, 0, stream>>>(bsums, nbN);
    k_scanC<<<nbN, BS, 0, stream>>>(offs, bsums, N, ETOT);

    k_cvt_x<<<(Npad + 7) / 8, BS, 0, stream>>>(x_base, cell_ids, cell_emb, xb, N, Npad);
    k_cvt_w12<<<(128 * 160 + 128 * 128 + BS - 1) / BS, BS, 0, stream>>>(W1, W2, Wt1, Wt2);

    // ---- layer 1
    k_gemm_mfma<160><<<gridG, 64, 0, stream>>>(xb, Wt1, a_src1, a_dst1, hb, as_, ad_, N);
    k_edgeww<<<nbN, BS, 0, stream>>>(head, nxt2, offs, as_, ad_, sw, N);
    k_agg<true, true><<<(N + 3) / 4, 256, 0, stream>>>(
        hb, sw, offs, b1, ln_g, ln_b, (void*)yb, N);

    // ---- layer 2
    k_gemm_mfma<128><<<gridG, 64, 0, stream>>>(yb, Wt2, a_src2, a_dst2, hb, as_, ad_, N);
    k_edgeww<<<nbN, BS, 0, stream>>>(head, nxt2, offs, as_, ad_, sw, N);
    k_agg<false, false><<<(N + 3) / 4, 256, 0, stream>>>(
        hb, sw, offs, b2, ln_g, ln_b, d_out, N);
}